// Round 8
// baseline (522.872 us; speedup 1.0000x reference)
//
#include <hip/hip_runtime.h>
#include <hip/hip_cooperative_groups.h>
#include <math.h>

namespace cg = cooperative_groups;

// CapsuleLayer dynamic routing. B=256, IN=1152, K=8, J=10, D=16, 3 passes.
//
// SINGLE cooperative kernel (512 blocks x 256 thr, 2/CU co-resident):
//   prep:  W -> wht bf16 [i][jd][k]*0.25 (k-replication: all 4 K-quads load
//          the same 8-k fragment -> u = 4*(x*W/4), exact pow2 scaling);
//          x -> xht bf16 [i][b][k]. Both via coalesced LDS transposes.
//   grid.sync
//   pass 0..2: [pass>0: every block redundantly reduces the 32 s_part slabs
//          for its OWN 16 batches + squash -> vdl in LDS (bitwise identical
//          across blocks, deterministic)];
//          compute partial s for (islab: 36 i) x (16 b) with
//          mfma_f32_16x16x32_bf16 (r5-r7-verified fragment math: C col=b,
//          row=d-quad, tile=j; logit = 4 in-lane FMA + shfl 16/32; softmax
//          in-lane over 10 j); 4-wave LDS reduce -> s_part slab;
//          fence + grid.sync.
//   final: squash 40960 elems (80 per block) -> out.
// Algebra: logits at pass t = (sum of previous v)·u_hat; pass 0 c = 0.1.

typedef float f32x4 __attribute__((ext_vector_type(4)));
typedef short bf16x8 __attribute__((ext_vector_type(8)));

#define B_TOT 256
#define IN_CAPS 1152
#define OUT_CAPS 10
#define JD 160

#define NBLK 512
#define NSLAB 32           // i-slabs of 36 i (islab = bid>>4)
#define IPB 36
#define SLI 12             // i per staged slice (3 slices)
#define REDS 164

#define WHT_BYTES (1152ull * 160 * 8 * 2)             // 2,949,120
#define XHT_BYTES (1152ull * 256 * 8 * 2)             // 4,718,592
#define SP_BYTES  ((size_t)NSLAB * B_TOT * JD * 4)    // 5,242,880
#define WS_NEED   (WHT_BYTES + XHT_BYTES + SP_BYTES)  // 12,910,592

static __device__ __forceinline__ unsigned f2bf(float f) {
    unsigned u = __float_as_uint(f);
    return (u + 0x7FFFu + ((u >> 16) & 1u)) >> 16;
}

__global__ __launch_bounds__(256, 2)
void caps_coop(const float* __restrict__ x, const float* __restrict__ W,
               unsigned short* __restrict__ wht, unsigned short* __restrict__ xht,
               float* __restrict__ s_part, float* __restrict__ out) {
    __shared__ __align__(16) unsigned short wsl[SLI * 1280];   // 30,720 B
    __shared__ __align__(16) unsigned short xsl[SLI * 16 * 8]; //  3,072 B
    __shared__ __align__(16) float red[2 * 16 * REDS];         // 20,992 B
    __shared__ __align__(16) float vdl[16 * REDS];             // 10,496 B

    cg::grid_group grid = cg::this_grid();
    const int tid = threadIdx.x;
    const int bid = blockIdx.x;

    // ================= prep: 288 W-units (4 i) + 576 x-units (8 i x 64 b) ===
    float* plds = (float*)wsl;
    for (int u = bid; u < 864; u += NBLK) {
        __syncthreads();
        if (u < 288) {
            const int i0 = u * 4;
            const f32x4* src = (const f32x4*)(W + (size_t)i0 * 1280);
            for (int c = tid; c < 1280; c += 256)
                *(f32x4*)(plds + c * 4) = src[c];                 // coalesced
            __syncthreads();
            for (int c = tid; c < 2560; c += 256) {
                const int i_l = c / 640, p = c % 640;
                const int jd = p >> 2, kp = p & 3;
                const int j = jd >> 4, d = jd & 15;
                const float* base = plds + i_l * 1280 + j * 128 + d;
                const unsigned lo = f2bf(base[(2 * kp) * 16] * 0.25f);
                const unsigned hi = f2bf(base[(2 * kp + 1) * 16] * 0.25f);
                ((unsigned*)wht)[(size_t)i0 * 640 + c] = lo | (hi << 16);
            }
        } else {
            const int v = u - 288;
            const int it = v >> 2, bt4 = v & 3;
            const int i0 = it * 8, b0p = bt4 * 64;
            for (int c = tid; c < 1024; c += 256) {
                const int bl = c >> 4, cf = c & 15;
                f32x4 vv = *(const f32x4*)(x + (size_t)(b0p + bl) * 9216 + i0 * 8 + cf * 4);
                *(f32x4*)(plds + bl * 68 + cf * 4) = vv;          // coalesced
            }
            __syncthreads();
            for (int c = tid; c < 512; c += 256) {
                const int i_l = c >> 6, b_l = c & 63;
                const float* r = plds + b_l * 68 + i_l * 8;
                uint4 o;
                o.x = f2bf(r[0]) | (f2bf(r[1]) << 16);
                o.y = f2bf(r[2]) | (f2bf(r[3]) << 16);
                o.z = f2bf(r[4]) | (f2bf(r[5]) << 16);
                o.w = f2bf(r[6]) | (f2bf(r[7]) << 16);
                ((uint4*)xht)[(size_t)(i0 + i_l) * 256 + b0p + b_l] = o;   // 1KB runs
            }
        }
    }
    __threadfence();
    grid.sync();                                   // S1: prep done

    // ================= routing passes =================
    const int l = tid & 63;
    const int w = tid >> 6;            // wave 0..3 (splits i)
    const int m = l & 15;              // b within tile / A-row / C-col
    const int q = l >> 4;              // k-quad (replicated) / d-quad (out)
    const int islab = bid >> 4;        // 0..31
    const int b0 = (bid & 15) * 16;
    const int b = b0 + m;

    for (int pass = 0; pass < 3; ++pass) {
        // ---- redundant in-block reduce+squash of previous pass -> vdl ----
        if (pass > 0) {
            const int b_l = tid >> 4, dd = tid & 15;
            float sacc[10];
            #pragma unroll
            for (int jj = 0; jj < 10; ++jj) sacc[jj] = 0.f;
            #pragma unroll 4
            for (int p = 0; p < NSLAB; ++p) {
                const float* sp = s_part + (size_t)p * (B_TOT * JD) + (b0 + b_l) * JD + dd;
                #pragma unroll
                for (int jj = 0; jj < 10; ++jj) sacc[jj] += sp[jj * 16];
            }
            #pragma unroll
            for (int jj = 0; jj < 10; ++jj) {
                float tt = sacc[jj] * sacc[jj];
                tt += __shfl_xor(tt, 1);
                tt += __shfl_xor(tt, 2);
                tt += __shfl_xor(tt, 4);
                tt += __shfl_xor(tt, 8);
                const float sc = tt / (1.0f + tt) / sqrtf(tt + 1e-7f);
                const float vv = sc * sacc[jj];
                if (pass == 1) vdl[b_l * REDS + jj * 16 + dd] = vv;
                else           vdl[b_l * REDS + jj * 16 + dd] += vv;
            }
            __syncthreads();
        }

        f32x4 vd[10];
        if (pass > 0) {
            #pragma unroll
            for (int jt = 0; jt < 10; ++jt)
                vd[jt] = *(const f32x4*)(vdl + m * REDS + jt * 16 + q * 4);
        }

        f32x4 s[10];
        #pragma unroll
        for (int jt = 0; jt < 10; ++jt) s[jt] = (f32x4){0.f, 0.f, 0.f, 0.f};

        #pragma unroll 1
        for (int sl3 = 0; sl3 < 3; ++sl3) {
            const int i0 = islab * IPB + sl3 * SLI;
            __syncthreads();
            {   // stage W slice: 12 i x 160 uint4, coalesced
                const uint4* src = (const uint4*)wht + (size_t)i0 * 160;
                uint4* dst = (uint4*)wsl;
                for (int c = tid; c < SLI * 160; c += 256) dst[c] = src[c];
            }
            {   // stage x slice: 12 i x 16 b
                uint4* dst = (uint4*)xsl;
                for (int c = tid; c < SLI * 16; c += 256) {
                    const int il = c >> 4, bl = c & 15;
                    dst[c] = ((const uint4*)xht)[(size_t)(i0 + il) * 256 + b0 + bl];
                }
            }
            __syncthreads();

            #pragma unroll 1
            for (int ii = 0; ii < 3; ++ii) {
                const int il = w * 3 + ii;
                const bf16x8 xb = *(const bf16x8*)(xsl + (il * 16 + m) * 8);
                f32x4 u[10];
                #pragma unroll
                for (int jt = 0; jt < 10; ++jt) {
                    const bf16x8 af = *(const bf16x8*)(wsl + (il * 160 + jt * 16 + m) * 8);
                    u[jt] = __builtin_amdgcn_mfma_f32_16x16x32_bf16(
                                af, xb, (f32x4){0.f, 0.f, 0.f, 0.f}, 0, 0, 0);
                }
                if (pass == 0) {
                    #pragma unroll
                    for (int jt = 0; jt < 10; ++jt) s[jt] += 0.1f * u[jt];
                } else {
                    float L[10];
                    #pragma unroll
                    for (int jt = 0; jt < 10; ++jt) {
                        const f32x4 p = vd[jt] * u[jt];
                        float e = (p.x + p.y) + (p.z + p.w);
                        e += __shfl_xor(e, 16);
                        e += __shfl_xor(e, 32);
                        L[jt] = e;
                    }
                    float mx = L[0];
                    #pragma unroll
                    for (int jt = 1; jt < 10; ++jt) mx = fmaxf(mx, L[jt]);
                    float Z = 0.f;
                    #pragma unroll
                    for (int jt = 0; jt < 10; ++jt) { L[jt] = __expf(L[jt] - mx); Z += L[jt]; }
                    const float inv = 1.0f / Z;
                    #pragma unroll
                    for (int jt = 0; jt < 10; ++jt) s[jt] += (L[jt] * inv) * u[jt];
                }
            }
        }

        // ---- 4-wave tree reduce through LDS -> s_part slab ----
        __syncthreads();
        if (w >= 2) {
            float* rp = red + (w - 2) * (16 * REDS) + m * REDS + q * 4;
            #pragma unroll
            for (int jt = 0; jt < 10; ++jt) *(f32x4*)(rp + jt * 16) = s[jt];
        }
        __syncthreads();
        if (w < 2) {
            const float* rp = red + w * (16 * REDS) + m * REDS + q * 4;
            #pragma unroll
            for (int jt = 0; jt < 10; ++jt) s[jt] += *(const f32x4*)(rp + jt * 16);
        }
        __syncthreads();
        if (w == 1) {
            float* rp = red + m * REDS + q * 4;
            #pragma unroll
            for (int jt = 0; jt < 10; ++jt) *(f32x4*)(rp + jt * 16) = s[jt];
        }
        __syncthreads();
        if (w == 0) {
            const float* rp = red + m * REDS + q * 4;
            #pragma unroll
            for (int jt = 0; jt < 10; ++jt) s[jt] += *(const f32x4*)(rp + jt * 16);
            float* sp = s_part + ((size_t)islab * B_TOT + b) * JD;
            #pragma unroll
            for (int jt = 0; jt < 10; ++jt)
                *(f32x4*)(sp + jt * 16 + q * 4) = s[jt];
        }

        __threadfence();
        grid.sync();                               // S2/S3/S4
    }

    // ================= final squash -> out =================
    if (tid < 80) {
        const int e = bid * 80 + tid;              // 512*80 = 40960
        float sv = 0.f;
        #pragma unroll 8
        for (int p = 0; p < NSLAB; ++p)
            sv += s_part[(size_t)p * (B_TOT * JD) + e];
        float tt = sv * sv;
        tt += __shfl_xor(tt, 1);
        tt += __shfl_xor(tt, 2);
        tt += __shfl_xor(tt, 4);
        tt += __shfl_xor(tt, 8);
        const float sc = tt / (1.0f + tt) / sqrtf(tt + 1e-7f);
        out[e] = sc * sv;
    }
}

// ---------- fallback: round-1 fused kernel (if coop launch unavailable) ----------
#define FB_NGROUPS 32
#define FB_THREADS (FB_NGROUPS * 16)
#define FB_ITERS (IN_CAPS / FB_NGROUPS)
__global__ __launch_bounds__(FB_THREADS)
void caps_routing_kernel(const float* __restrict__ x, const float* __restrict__ W,
                         float* __restrict__ out) {
    __shared__ __align__(16) float xsf[IN_CAPS * 8];
    __shared__ float sredf[FB_NGROUPS * JD];
    __shared__ float vdot_lds[JD];
    const int b = blockIdx.x, tid = threadIdx.x;
    const int g = tid >> 4, d = tid & 15;
    {
        const float4* xg = reinterpret_cast<const float4*>(x + (size_t)b * IN_CAPS * 8);
        float4* xl = reinterpret_cast<float4*>(xsf);
        for (int t = tid; t < IN_CAPS * 2; t += FB_THREADS) xl[t] = xg[t];
    }
    __syncthreads();
    for (int pass = 0; pass < 3; ++pass) {
        float vdot_reg[OUT_CAPS];
        if (pass > 0) {
            #pragma unroll
            for (int j = 0; j < OUT_CAPS; ++j) vdot_reg[j] = vdot_lds[j * 16 + d];
        }
        float s_loc[OUT_CAPS];
        #pragma unroll
        for (int j = 0; j < OUT_CAPS; ++j) s_loc[j] = 0.f;
        for (int it = 0; it < FB_ITERS; ++it) {
            const int i = it * FB_NGROUPS + g;
            float xk[8];
            {
                const float4* xr = reinterpret_cast<const float4*>(xsf + i * 8);
                float4 a0 = xr[0], a1 = xr[1];
                xk[0]=a0.x; xk[1]=a0.y; xk[2]=a0.z; xk[3]=a0.w;
                xk[4]=a1.x; xk[5]=a1.y; xk[6]=a1.z; xk[7]=a1.w;
            }
            const float* wpf = W + (size_t)i * 1280 + d;
            float u[OUT_CAPS];
            #pragma unroll
            for (int j = 0; j < OUT_CAPS; ++j) {
                float acc = 0.f;
                #pragma unroll
                for (int k = 0; k < 8; ++k) acc = fmaf(xk[k], wpf[j * 128 + k * 16], acc);
                u[j] = acc;
            }
            if (pass == 0) {
                #pragma unroll
                for (int j = 0; j < OUT_CAPS; ++j) s_loc[j] = fmaf(0.1f, u[j], s_loc[j]);
            } else {
                float logit[OUT_CAPS];
                #pragma unroll
                for (int j = 0; j < OUT_CAPS; ++j) {
                    float t2 = vdot_reg[j] * u[j];
                    t2 += __shfl_xor(t2, 1); t2 += __shfl_xor(t2, 2);
                    t2 += __shfl_xor(t2, 4); t2 += __shfl_xor(t2, 8);
                    logit[j] = t2;
                }
                float mm = logit[0];
                #pragma unroll
                for (int j = 1; j < OUT_CAPS; ++j) mm = fmaxf(mm, logit[j]);
                float Z = 0.f, e[OUT_CAPS];
                #pragma unroll
                for (int j = 0; j < OUT_CAPS; ++j) { e[j] = expf(logit[j] - mm); Z += e[j]; }
                const float invZ = 1.0f / Z;
                #pragma unroll
                for (int j = 0; j < OUT_CAPS; ++j) s_loc[j] = fmaf(e[j] * invZ, u[j], s_loc[j]);
            }
        }
        #pragma unroll
        for (int j = 0; j < OUT_CAPS; ++j) sredf[g * JD + j * 16 + d] = s_loc[j];
        __syncthreads();
        if (tid < JD) {
            float sv = 0.f;
            #pragma unroll 8
            for (int gg = 0; gg < FB_NGROUPS; ++gg) sv += sredf[gg * JD + tid];
            float t2 = sv * sv;
            t2 += __shfl_xor(t2, 1); t2 += __shfl_xor(t2, 2);
            t2 += __shfl_xor(t2, 4); t2 += __shfl_xor(t2, 8);
            const float scale = t2 / (1.0f + t2) / sqrtf(t2 + 1e-7f);
            const float v = scale * sv;
            if (pass == 2) out[(size_t)b * JD + tid] = v;
            else vdot_lds[tid] = (pass == 0) ? v : (vdot_lds[tid] + v);
        }
        __syncthreads();
    }
}

extern "C" void kernel_launch(void* const* d_in, const int* in_sizes, int n_in,
                              void* d_out, int out_size, void* d_ws, size_t ws_size,
                              hipStream_t stream) {
    const float* x = (const float*)d_in[0];
    const float* W = (const float*)d_in[1];
    float* out = (float*)d_out;

    if (ws_size >= WS_NEED) {
        unsigned short* wht = (unsigned short*)d_ws;
        unsigned short* xht = (unsigned short*)((char*)d_ws + WHT_BYTES);
        float* s_part = (float*)((char*)d_ws + WHT_BYTES + XHT_BYTES);

        void* args[6];
        args[0] = (void*)&x;
        args[1] = (void*)&W;
        args[2] = (void*)&wht;
        args[3] = (void*)&xht;
        args[4] = (void*)&s_part;
        args[5] = (void*)&out;
        hipError_t err = hipLaunchCooperativeKernel((const void*)caps_coop,
                                                    dim3(NBLK), dim3(256),
                                                    args, 0, stream);
        if (err == hipSuccess) return;
        // fall through to fallback if cooperative launch was rejected
    }
    caps_routing_kernel<<<B_TOT, FB_THREADS, 0, stream>>>(x, W, out);
}

// Round 9
// 98.419 us; speedup vs baseline: 5.3127x; 5.3127x over previous
//
#include <hip/hip_runtime.h>
#include <math.h>

// CapsuleLayer dynamic routing. B=256, IN=1152, K=8, J=10, D=16, 3 passes.
//
// 4 kernels, no grid.sync, no prep kernels:
//  caps_pass<0>: per block (islab of 72 i x 16 b): convert W f32 -> bf16*0.25
//    (k-replication: all 4 K-quads of the MFMA read the same 8-k fragment ->
//    u = 4*(x*W/4), exact) straight into LDS, chunked 24 i; btile==0 blocks
//    also publish wht bf16 to ws (next kernels read it; ordered by kernel
//    boundary). x converted in-kernel. 10x mfma_f32_16x16x32_bf16 per i
//    (layout verified r5-r7: C col=b, row=d-quad, tile=j). c==0.1 exactly.
//    8-wave LDS tree reduce -> spA slab.
//  caps_pass<1>: redundant per-block squash of spA (its own 16 b) -> v0 in
//    LDS -> vd regs (islab==0 publishes v0 -> vdot_g); compute -> spB.
//  caps_pass<2>: squash spB -> v1; vd = vdot_g + v1; compute -> spA.
//  sq_final: reduce 16 spA slabs + squash -> out.
// Algebra: logits at pass t = (sum of previous v)·u_hat; pass 0 c = 0.1.

typedef float f32x4 __attribute__((ext_vector_type(4)));
typedef short bf16x8 __attribute__((ext_vector_type(8)));

#define B_TOT 256
#define IN_CAPS 1152
#define OUT_CAPS 10
#define JD 160

#define NSLAB 16
#define IPB 72             // i per block
#define CHUNK 24           // i per staged LDS chunk (3 chunks)
#define THREADS 512

// LDS regions (bytes)
#define WSL_B   (CHUNK * 1280 * 2)       // 61,440
#define XALL_B  (IPB * 16 * 8 * 2)       // 18,432
#define SMEM_B  (WSL_B + XALL_B)         // 79,872
#define RAWS 168                          // raw sum row stride (floats)
#define REDS 164                          // vdl / reduce row stride (floats)

#define WHT_BYTES (1152ull * 160 * 8 * 2)             // 2,949,120
#define SP_BYTES  ((size_t)NSLAB * B_TOT * JD * 4)    // 2,621,440
#define VG_BYTES  ((size_t)B_TOT * JD * 4)            // 163,840
#define WS_NEED   (WHT_BYTES + 2 * SP_BYTES + VG_BYTES)

static __device__ __forceinline__ unsigned f2bf(float f) {
    unsigned u = __float_as_uint(f);
    return (u + 0x7FFFu + ((u >> 16) & 1u)) >> 16;
}

template<int PASS>
__global__ __launch_bounds__(THREADS)
void caps_pass(const float* __restrict__ x, const float* __restrict__ W,
               unsigned* __restrict__ wht,        // bf16 pairs as u32
               const float* __restrict__ s_in,    // prev s_part (PASS>0)
               float* __restrict__ s_out,
               float* __restrict__ vdot_g) {
    __shared__ __align__(16) unsigned char smem[SMEM_B];
    unsigned short* wsl  = (unsigned short*)smem;            // [CHUNK][160][8]
    unsigned short* xAll = (unsigned short*)(smem + WSL_B);  // [72][16][8]
    float* raw = (float*)smem;                               // [16][RAWS]
    float* vdl = (float*)(smem + 16 * RAWS * 4);             // [16][REDS]
    float* red = (float*)smem;                               // 4 x [16][REDS]

    const int tid = threadIdx.x;
    const int l = tid & 63;
    const int w = tid >> 6;            // wave 0..7 (splits i)
    const int m = l & 15;              // b in tile / A-row / C-col
    const int q = l >> 4;              // k-quad (replicated) / d-quad (out)
    const int islab = blockIdx.x;      // 0..15
    const int btile = blockIdx.y;      // 0..15
    const int b0 = btile * 16;
    const int i0 = islab * IPB;

    // ---- stage xAll: x[b0..+16][i0..+72][8] f32 -> bf16 [i][b][k] ----
    for (int c = tid; c < 16 * IPB; c += THREADS) {
        const int bl = c / IPB, il = c % IPB;
        const float* xp = x + (size_t)(b0 + bl) * 9216 + (size_t)(i0 + il) * 8;
        const f32x4 a0 = *(const f32x4*)xp, a1 = *(const f32x4*)(xp + 4);
        uint4 o;
        o.x = f2bf(a0.x) | (f2bf(a0.y) << 16);
        o.y = f2bf(a0.z) | (f2bf(a0.w) << 16);
        o.z = f2bf(a1.x) | (f2bf(a1.y) << 16);
        o.w = f2bf(a1.z) | (f2bf(a1.w) << 16);
        ((uint4*)xAll)[il * 16 + bl] = o;
    }

    // ---- PASS>0: redundant squash of s_in for our 16 batches ----
    f32x4 vd[10];
    if (PASS > 0) {
        #pragma unroll
        for (int c = 0; c < 5; ++c) {
            const int e = c * THREADS + tid;           // 0..2559, coalesced
            float acc = 0.f;
            #pragma unroll
            for (int p = 0; p < NSLAB; ++p)
                acc += s_in[(size_t)p * (B_TOT * JD) + b0 * JD + e];
            raw[(e / JD) * RAWS + (e % JD)] = acc;
        }
        __syncthreads();
        if (tid < 256) {
            const int b_l = tid >> 4, dd = tid & 15;
            #pragma unroll
            for (int jj = 0; jj < 10; ++jj) {
                const float sv = raw[b_l * RAWS + jj * 16 + dd];
                float tt = sv * sv;
                tt += __shfl_xor(tt, 1);
                tt += __shfl_xor(tt, 2);
                tt += __shfl_xor(tt, 4);
                tt += __shfl_xor(tt, 8);
                const float sc = tt / (1.0f + tt) / sqrtf(tt + 1e-7f);
                float vv = sc * sv;
                if (PASS == 1) {
                    if (islab == 0)
                        vdot_g[(size_t)(b0 + b_l) * JD + jj * 16 + dd] = vv;  // publish v0
                } else {
                    vv += vdot_g[(size_t)(b0 + b_l) * JD + jj * 16 + dd];     // v0 + v1
                }
                vdl[b_l * REDS + jj * 16 + dd] = vv;
            }
        }
        __syncthreads();
        #pragma unroll
        for (int jt = 0; jt < 10; ++jt)
            vd[jt] = *(const f32x4*)(vdl + m * REDS + jt * 16 + q * 4);
    }

    f32x4 s[10];
    #pragma unroll
    for (int jt = 0; jt < 10; ++jt) s[jt] = (f32x4){0.f, 0.f, 0.f, 0.f};

    // ---- 3 chunks of 24 i ----
    #pragma unroll 1
    for (int ch = 0; ch < 3; ++ch) {
        __syncthreads();    // protect wsl region (vdl/raw dead; prev chunk read done)
        if (PASS == 0) {
            // convert W f32 -> bf16*0.25, LDS-contiguous writes, 512B global runs
            for (int c = tid; c < CHUNK * 640; c += THREADS) {
                const int i_l = c / 640, r = c % 640;
                const int jd = r >> 2, kp = r & 3;
                const int j = jd >> 4, d = jd & 15;
                const int ig = i0 + ch * CHUNK + i_l;
                const float* bp = W + (size_t)ig * 1280 + j * 128 + d;
                const unsigned lo = f2bf(bp[(2 * kp) * 16] * 0.25f);
                const unsigned hi = f2bf(bp[(2 * kp + 1) * 16] * 0.25f);
                const unsigned word = lo | (hi << 16);
                ((unsigned*)wsl)[c] = word;
                if (btile == 0) wht[(size_t)ig * 640 + r] = word;   // publish
            }
        } else {
            const uint4* src = (const uint4*)wht + (size_t)(i0 + ch * CHUNK) * 160;
            uint4* dst = (uint4*)wsl;
            for (int c = tid; c < CHUNK * 160; c += THREADS) dst[c] = src[c];
        }
        __syncthreads();

        #pragma unroll 1
        for (int ii = 0; ii < 3; ++ii) {
            const int il = w * 3 + ii;                    // 0..23
            const bf16x8 xb = *(const bf16x8*)(xAll + ((ch * CHUNK + il) * 16 + m) * 8);
            f32x4 u[10];
            #pragma unroll
            for (int jt = 0; jt < 10; ++jt) {
                const bf16x8 af = *(const bf16x8*)(wsl + (il * 160 + jt * 16 + m) * 8);
                u[jt] = __builtin_amdgcn_mfma_f32_16x16x32_bf16(
                            af, xb, (f32x4){0.f, 0.f, 0.f, 0.f}, 0, 0, 0);
            }
            if (PASS == 0) {
                #pragma unroll
                for (int jt = 0; jt < 10; ++jt) s[jt] += 0.1f * u[jt];
            } else {
                float L[10];
                #pragma unroll
                for (int jt = 0; jt < 10; ++jt) {
                    const f32x4 p = vd[jt] * u[jt];
                    float e = (p.x + p.y) + (p.z + p.w);
                    e += __shfl_xor(e, 16);
                    e += __shfl_xor(e, 32);
                    L[jt] = e;
                }
                float mx = L[0];
                #pragma unroll
                for (int jt = 1; jt < 10; ++jt) mx = fmaxf(mx, L[jt]);
                float Z = 0.f;
                #pragma unroll
                for (int jt = 0; jt < 10; ++jt) { L[jt] = __expf(L[jt] - mx); Z += L[jt]; }
                const float inv = 1.0f / Z;
                #pragma unroll
                for (int jt = 0; jt < 10; ++jt) s[jt] += (L[jt] * inv) * u[jt];
            }
        }
    }

    // ---- 8-wave tree reduce through LDS (wsl/xAll dead) -> s_out slab ----
    __syncthreads();
    if (w >= 4) {
        float* rp = red + (w - 4) * (16 * REDS) + m * REDS + q * 4;
        #pragma unroll
        for (int jt = 0; jt < 10; ++jt) *(f32x4*)(rp + jt * 16) = s[jt];
    }
    __syncthreads();
    if (w < 4) {
        const float* rp = red + w * (16 * REDS) + m * REDS + q * 4;
        #pragma unroll
        for (int jt = 0; jt < 10; ++jt) s[jt] += *(const f32x4*)(rp + jt * 16);
    }
    __syncthreads();
    if (w >= 2 && w < 4) {
        float* rp = red + (w - 2) * (16 * REDS) + m * REDS + q * 4;
        #pragma unroll
        for (int jt = 0; jt < 10; ++jt) *(f32x4*)(rp + jt * 16) = s[jt];
    }
    __syncthreads();
    if (w < 2) {
        const float* rp = red + w * (16 * REDS) + m * REDS + q * 4;
        #pragma unroll
        for (int jt = 0; jt < 10; ++jt) s[jt] += *(const f32x4*)(rp + jt * 16);
    }
    __syncthreads();
    if (w == 1) {
        float* rp = red + m * REDS + q * 4;
        #pragma unroll
        for (int jt = 0; jt < 10; ++jt) *(f32x4*)(rp + jt * 16) = s[jt];
    }
    __syncthreads();
    if (w == 0) {
        const float* rp = red + m * REDS + q * 4;
        #pragma unroll
        for (int jt = 0; jt < 10; ++jt) s[jt] += *(const f32x4*)(rp + jt * 16);
        float* sp = s_out + ((size_t)islab * B_TOT + b0 + m) * JD;
        #pragma unroll
        for (int jt = 0; jt < 10; ++jt)
            *(f32x4*)(sp + jt * 16 + q * 4) = s[jt];
    }
}

__global__ __launch_bounds__(256)
void sq_final(const float* __restrict__ s_part, float* __restrict__ out) {
    const int e = blockIdx.x * 256 + threadIdx.x;    // < 40960
    float s = 0.f;
    #pragma unroll
    for (int p = 0; p < NSLAB; ++p)
        s += s_part[(size_t)p * (B_TOT * JD) + e];
    float t = s * s;
    t += __shfl_xor(t, 1);
    t += __shfl_xor(t, 2);
    t += __shfl_xor(t, 4);
    t += __shfl_xor(t, 8);
    const float scale = t / (1.0f + t) / sqrtf(t + 1e-7f);
    out[e] = scale * s;
}

// ---------- fallback: round-1 fused kernel (ws too small; shouldn't happen) ----------
#define FB_NGROUPS 32
#define FB_THREADS (FB_NGROUPS * 16)
#define FB_ITERS (IN_CAPS / FB_NGROUPS)
__global__ __launch_bounds__(FB_THREADS)
void caps_routing_kernel(const float* __restrict__ x, const float* __restrict__ W,
                         float* __restrict__ out) {
    __shared__ __align__(16) float xsf[IN_CAPS * 8];
    __shared__ float sredf[FB_NGROUPS * JD];
    __shared__ float vdot_lds[JD];
    const int b = blockIdx.x, tid = threadIdx.x;
    const int g = tid >> 4, d = tid & 15;
    {
        const float4* xg = reinterpret_cast<const float4*>(x + (size_t)b * IN_CAPS * 8);
        float4* xl = reinterpret_cast<float4*>(xsf);
        for (int t = tid; t < IN_CAPS * 2; t += FB_THREADS) xl[t] = xg[t];
    }
    __syncthreads();
    for (int pass = 0; pass < 3; ++pass) {
        float vdot_reg[OUT_CAPS];
        if (pass > 0) {
            #pragma unroll
            for (int j = 0; j < OUT_CAPS; ++j) vdot_reg[j] = vdot_lds[j * 16 + d];
        }
        float s_loc[OUT_CAPS];
        #pragma unroll
        for (int j = 0; j < OUT_CAPS; ++j) s_loc[j] = 0.f;
        for (int it = 0; it < FB_ITERS; ++it) {
            const int i = it * FB_NGROUPS + g;
            float xk[8];
            {
                const float4* xr = reinterpret_cast<const float4*>(xsf + i * 8);
                float4 a0 = xr[0], a1 = xr[1];
                xk[0]=a0.x; xk[1]=a0.y; xk[2]=a0.z; xk[3]=a0.w;
                xk[4]=a1.x; xk[5]=a1.y; xk[6]=a1.z; xk[7]=a1.w;
            }
            const float* wpf = W + (size_t)i * 1280 + d;
            float u[OUT_CAPS];
            #pragma unroll
            for (int j = 0; j < OUT_CAPS; ++j) {
                float acc = 0.f;
                #pragma unroll
                for (int k = 0; k < 8; ++k) acc = fmaf(xk[k], wpf[j * 128 + k * 16], acc);
                u[j] = acc;
            }
            if (pass == 0) {
                #pragma unroll
                for (int j = 0; j < OUT_CAPS; ++j) s_loc[j] = fmaf(0.1f, u[j], s_loc[j]);
            } else {
                float logit[OUT_CAPS];
                #pragma unroll
                for (int j = 0; j < OUT_CAPS; ++j) {
                    float t2 = vdot_reg[j] * u[j];
                    t2 += __shfl_xor(t2, 1); t2 += __shfl_xor(t2, 2);
                    t2 += __shfl_xor(t2, 4); t2 += __shfl_xor(t2, 8);
                    logit[j] = t2;
                }
                float mm = logit[0];
                #pragma unroll
                for (int j = 1; j < OUT_CAPS; ++j) mm = fmaxf(mm, logit[j]);
                float Z = 0.f, e[OUT_CAPS];
                #pragma unroll
                for (int j = 0; j < OUT_CAPS; ++j) { e[j] = expf(logit[j] - mm); Z += e[j]; }
                const float invZ = 1.0f / Z;
                #pragma unroll
                for (int j = 0; j < OUT_CAPS; ++j) s_loc[j] = fmaf(e[j] * invZ, u[j], s_loc[j]);
            }
        }
        #pragma unroll
        for (int j = 0; j < OUT_CAPS; ++j) sredf[g * JD + j * 16 + d] = s_loc[j];
        __syncthreads();
        if (tid < JD) {
            float sv = 0.f;
            #pragma unroll 8
            for (int gg = 0; gg < FB_NGROUPS; ++gg) sv += sredf[gg * JD + tid];
            float t2 = sv * sv;
            t2 += __shfl_xor(t2, 1); t2 += __shfl_xor(t2, 2);
            t2 += __shfl_xor(t2, 4); t2 += __shfl_xor(t2, 8);
            const float scale = t2 / (1.0f + t2) / sqrtf(t2 + 1e-7f);
            const float v = scale * sv;
            if (pass == 2) out[(size_t)b * JD + tid] = v;
            else vdot_lds[tid] = (pass == 0) ? v : (vdot_lds[tid] + v);
        }
        __syncthreads();
    }
}

extern "C" void kernel_launch(void* const* d_in, const int* in_sizes, int n_in,
                              void* d_out, int out_size, void* d_ws, size_t ws_size,
                              hipStream_t stream) {
    const float* x = (const float*)d_in[0];
    const float* W = (const float*)d_in[1];
    float* out = (float*)d_out;

    if (ws_size >= WS_NEED) {
        unsigned* wht = (unsigned*)d_ws;
        float* spA    = (float*)((char*)d_ws + WHT_BYTES);
        float* spB    = (float*)((char*)d_ws + WHT_BYTES + SP_BYTES);
        float* vdot_g = (float*)((char*)d_ws + WHT_BYTES + 2 * SP_BYTES);

        const dim3 gR(NSLAB, 16);
        caps_pass<0><<<gR, THREADS, 0, stream>>>(x, W, wht, nullptr, spA, vdot_g);
        caps_pass<1><<<gR, THREADS, 0, stream>>>(x, W, wht, spA, spB, vdot_g);
        caps_pass<2><<<gR, THREADS, 0, stream>>>(x, W, wht, spB, spA, vdot_g);
        sq_final<<<(B_TOT * JD) / 256, 256, 0, stream>>>(spA, out);
    } else {
        caps_routing_kernel<<<B_TOT, FB_THREADS, 0, stream>>>(x, W, out);
    }
}

// Round 10
// 89.975 us; speedup vs baseline: 5.8113x; 1.0938x over previous
//
#include <hip/hip_runtime.h>
#include <math.h>

// CapsuleLayer dynamic routing. B=256, IN=1152, K=8, J=10, D=16, 3 passes.
//
// 7 kernels:
//  prep_all : (r7-verified) W -> wht bf16 [i][jd][k]*0.25 (k-replication:
//             all 4 K-quads read the same 8-k fragment -> u = 4*(x*W/4));
//             x -> xht bf16 [i][b][k]. Coalesced LDS transposes.
//  caps_pass<P>: grid (192 i-slabs of 6 i x 4 b-groups of 64), 256 thr.
//             Wave w owns b-tile w (16 b) — no cross-wave reduce. Per i:
//             10x mfma_f32_16x16x32_bf16 (C layout verified r5-r9: col=b,
//             row=d-quad, tile=j). P0: accumulator-chained MFMA, x0.1 at
//             store. P>0: logit = 4 in-lane FMA + shfl 16/32; softmax
//             in-lane (no max-sub: |logit| < 2, exp safe); s += c*u.
//             Direct slab store -> s_part[islab].
//  sq<P>    : reduce 192 slabs + squash -> vdot_g (P0: =v0, P1: +=v1) /
//             out (P2).
// Algebra: logits at pass t = (sum of previous v)·u_hat; pass 0 c = 0.1.

typedef float f32x4 __attribute__((ext_vector_type(4)));
typedef short bf16x8 __attribute__((ext_vector_type(8)));

#define B_TOT 256
#define IN_CAPS 1152
#define OUT_CAPS 10
#define JD 160

#define NSLAB 192
#define IPB 6              // i per block

#define WHT_BYTES (1152ull * 160 * 8 * 2)             // 2,949,120
#define XHT_BYTES (1152ull * 256 * 8 * 2)             // 4,718,592
#define SP_BYTES  ((size_t)NSLAB * B_TOT * JD * 4)    // 31,457,280
#define VD_BYTES  ((size_t)B_TOT * JD * 4)            // 163,840
#define WS_NEED   (WHT_BYTES + XHT_BYTES + 2 * SP_BYTES + VD_BYTES)

static __device__ __forceinline__ unsigned f2bf(float f) {
    unsigned u = __float_as_uint(f);
    return (u + 0x7FFFu + ((u >> 16) & 1u)) >> 16;
}

// ---------------- coalesced preps (r7-verified pattern) ----------------
#define PREPW_BLOCKS 288   // 4 i each
#define PREPX_BLOCKS 288   // 16 i x 64 b each

__global__ __launch_bounds__(256)
void prep_all(const float* __restrict__ x, const float* __restrict__ W,
              unsigned* __restrict__ whu, unsigned* __restrict__ xhu) {
    __shared__ __align__(16) float lds[64 * 132];   // 33,792 B
    const int bid = blockIdx.x, t = threadIdx.x;

    if (bid < PREPW_BLOCKS) {
        // ---- W path: 4 i per block ----
        const int i0 = bid * 4;
        const f32x4* src = (const f32x4*)(W + (size_t)i0 * 1280);
        for (int c = t; c < 1280; c += 256)
            *(f32x4*)(lds + c * 4) = src[c];          // coalesced read
        __syncthreads();
        for (int c = t; c < 2560; c += 256) {
            const int i_l = c / 640, p = c % 640;
            const int jd = p >> 2, kp = p & 3;        // k = 2*kp
            const int j = jd >> 4, d = jd & 15;
            const float* base = lds + i_l * 1280 + j * 128 + d;
            const unsigned lo = f2bf(base[(2 * kp) * 16] * 0.25f);
            const unsigned hi = f2bf(base[(2 * kp + 1) * 16] * 0.25f);
            whu[(size_t)i0 * 640 + c] = lo | (hi << 16);   // coalesced write
        }
    } else {
        // ---- x path: 16 i x 64 b tile ----
        const int bx = bid - PREPW_BLOCKS;
        const int it = bx >> 2;          // 72 i-tiles
        const int bt = bx & 3;           // 4 b-tiles of 64
        const int i0 = it * 16, b0 = bt * 64;
        for (int c = t; c < 2048; c += 256) {
            const int bl = c >> 5, cf = c & 31;
            f32x4 v = *(const f32x4*)(x + (size_t)(b0 + bl) * 9216 + i0 * 8 + cf * 4);
            *(f32x4*)(lds + bl * 132 + cf * 4) = v;   // coalesced read (512B runs)
        }
        __syncthreads();
        for (int c = t; c < 1024; c += 256) {
            const int i_l = c >> 6, b_l = c & 63;
            const float* r = lds + b_l * 132 + i_l * 8;
            uint4 o;
            o.x = f2bf(r[0]) | (f2bf(r[1]) << 16);
            o.y = f2bf(r[2]) | (f2bf(r[3]) << 16);
            o.z = f2bf(r[4]) | (f2bf(r[5]) << 16);
            o.w = f2bf(r[6]) | (f2bf(r[7]) << 16);
            ((uint4*)xhu)[(size_t)(i0 + i_l) * 256 + b0 + b_l] = o;  // 1KB runs
        }
    }
}

// ---------------- routing pass ----------------
template<int PASS>
__global__ __launch_bounds__(256, 3)
void caps_pass(const unsigned short* __restrict__ wht,
               const unsigned short* __restrict__ xht,
               const float* __restrict__ vdot_g,
               float* __restrict__ s_out) {
    __shared__ __align__(16) unsigned short wsl[IPB * 160 * 8];  // 15,360 B
    __shared__ __align__(16) unsigned short xsl[IPB * 64 * 8];   //  6,144 B

    const int t = threadIdx.x;
    const int l = t & 63;
    const int w = t >> 6;              // wave 0..3 = b-tile
    const int m = l & 15;              // b within tile / A-row / C-col
    const int q = l >> 4;              // k-quad (replicated) / d-quad (out)
    const int islab = blockIdx.x;      // 0..191
    const int b0 = blockIdx.y * 64;
    const int bg = b0 + w * 16 + m;
    const int i0 = islab * IPB;

    // ---- stage slabs (coalesced uint4) ----
    {
        const uint4* srcW = (const uint4*)wht + (size_t)i0 * 160;
        uint4* dW = (uint4*)wsl;
        for (int c = t; c < IPB * 160; c += 256) dW[c] = srcW[c];
        uint4* dX = (uint4*)xsl;
        for (int c = t; c < IPB * 64; c += 256) {
            const int il = c >> 6, bl = c & 63;
            dX[c] = ((const uint4*)xht)[(size_t)(i0 + il) * 256 + b0 + bl];
        }
    }

    // vdot fragments (i-invariant), from global (L2-hot), PASS >= 1
    f32x4 vd[10];
    if (PASS > 0) {
        #pragma unroll
        for (int jt = 0; jt < 10; ++jt)
            vd[jt] = *(const f32x4*)(vdot_g + (size_t)bg * JD + jt * 16 + q * 4);
    }

    f32x4 s[10];
    #pragma unroll
    for (int jt = 0; jt < 10; ++jt) s[jt] = (f32x4){0.f, 0.f, 0.f, 0.f};

    __syncthreads();

    #pragma unroll 1
    for (int il = 0; il < IPB; ++il) {
        const bf16x8 xb = *(const bf16x8*)(xsl + (il * 64 + w * 16 + m) * 8);

        if (PASS == 0) {
            // accumulator-chained MFMA: s += W_i^T x_i  (x0.1 at store)
            #pragma unroll
            for (int jt = 0; jt < 10; ++jt) {
                const bf16x8 af = *(const bf16x8*)(wsl + (il * 160 + jt * 16 + m) * 8);
                s[jt] = __builtin_amdgcn_mfma_f32_16x16x32_bf16(af, xb, s[jt], 0, 0, 0);
            }
        } else {
            f32x4 u[10];
            #pragma unroll
            for (int jt = 0; jt < 10; ++jt) {
                const bf16x8 af = *(const bf16x8*)(wsl + (il * 160 + jt * 16 + m) * 8);
                u[jt] = __builtin_amdgcn_mfma_f32_16x16x32_bf16(
                            af, xb, (f32x4){0.f, 0.f, 0.f, 0.f}, 0, 0, 0);
            }
            // logit[j] = sum_d vd.u (in-lane dot4 + cross-quad shfl 16/32)
            float L[10];
            #pragma unroll
            for (int jt = 0; jt < 10; ++jt) {
                const f32x4 p = vd[jt] * u[jt];
                float e = (p.x + p.y) + (p.z + p.w);
                e += __shfl_xor(e, 16);
                e += __shfl_xor(e, 32);
                L[jt] = e;
            }
            // softmax over 10 j, no max-sub (|L| < 2 by construction)
            float Z = 0.f;
            #pragma unroll
            for (int jt = 0; jt < 10; ++jt) { L[jt] = __expf(L[jt]); Z += L[jt]; }
            const float inv = 1.0f / Z;
            #pragma unroll
            for (int jt = 0; jt < 10; ++jt) s[jt] += (L[jt] * inv) * u[jt];
        }
    }

    if (PASS == 0) {
        #pragma unroll
        for (int jt = 0; jt < 10; ++jt) s[jt] *= 0.1f;
    }

    // wave owns its b-tile: direct slab store (64B granules per quad)
    float* sp = s_out + ((size_t)islab * B_TOT + bg) * JD;
    #pragma unroll
    for (int jt = 0; jt < 10; ++jt)
        *(f32x4*)(sp + jt * 16 + q * 4) = s[jt];
}

// ---------------- reduce + squash ----------------
template<int PASS>
__global__ __launch_bounds__(256)
void k_squash(const float* __restrict__ s_part,
              float* __restrict__ vdot_g, float* __restrict__ out) {
    const int e = blockIdx.x * 256 + threadIdx.x;    // < 40960
    float s = 0.f;
    #pragma unroll 8
    for (int p = 0; p < NSLAB; ++p)
        s += s_part[(size_t)p * (B_TOT * JD) + e];

    float t = s * s;
    t += __shfl_xor(t, 1);
    t += __shfl_xor(t, 2);
    t += __shfl_xor(t, 4);
    t += __shfl_xor(t, 8);
    const float scale = t / (1.0f + t) / sqrtf(t + 1e-7f);
    const float v = scale * s;

    if (PASS == 0)      vdot_g[e] = v;
    else if (PASS == 1) vdot_g[e] += v;
    else                out[e] = v;
}

// ---------- fallback: round-1 fused kernel (ws too small; shouldn't happen) ----------
#define FB_NGROUPS 32
#define FB_THREADS (FB_NGROUPS * 16)
#define FB_ITERS (IN_CAPS / FB_NGROUPS)
__global__ __launch_bounds__(FB_THREADS)
void caps_routing_kernel(const float* __restrict__ x, const float* __restrict__ W,
                         float* __restrict__ out) {
    __shared__ __align__(16) float xsf[IN_CAPS * 8];
    __shared__ float sredf[FB_NGROUPS * JD];
    __shared__ float vdot_lds[JD];
    const int b = blockIdx.x, tid = threadIdx.x;
    const int g = tid >> 4, d = tid & 15;
    {
        const float4* xg = reinterpret_cast<const float4*>(x + (size_t)b * IN_CAPS * 8);
        float4* xl = reinterpret_cast<float4*>(xsf);
        for (int t = tid; t < IN_CAPS * 2; t += FB_THREADS) xl[t] = xg[t];
    }
    __syncthreads();
    for (int pass = 0; pass < 3; ++pass) {
        float vdot_reg[OUT_CAPS];
        if (pass > 0) {
            #pragma unroll
            for (int j = 0; j < OUT_CAPS; ++j) vdot_reg[j] = vdot_lds[j * 16 + d];
        }
        float s_loc[OUT_CAPS];
        #pragma unroll
        for (int j = 0; j < OUT_CAPS; ++j) s_loc[j] = 0.f;
        for (int it = 0; it < FB_ITERS; ++it) {
            const int i = it * FB_NGROUPS + g;
            float xk[8];
            {
                const float4* xr = reinterpret_cast<const float4*>(xsf + i * 8);
                float4 a0 = xr[0], a1 = xr[1];
                xk[0]=a0.x; xk[1]=a0.y; xk[2]=a0.z; xk[3]=a0.w;
                xk[4]=a1.x; xk[5]=a1.y; xk[6]=a1.z; xk[7]=a1.w;
            }
            const float* wpf = W + (size_t)i * 1280 + d;
            float u[OUT_CAPS];
            #pragma unroll
            for (int j = 0; j < OUT_CAPS; ++j) {
                float acc = 0.f;
                #pragma unroll
                for (int k = 0; k < 8; ++k) acc = fmaf(xk[k], wpf[j * 128 + k * 16], acc);
                u[j] = acc;
            }
            if (pass == 0) {
                #pragma unroll
                for (int j = 0; j < OUT_CAPS; ++j) s_loc[j] = fmaf(0.1f, u[j], s_loc[j]);
            } else {
                float logit[OUT_CAPS];
                #pragma unroll
                for (int j = 0; j < OUT_CAPS; ++j) {
                    float t2 = vdot_reg[j] * u[j];
                    t2 += __shfl_xor(t2, 1); t2 += __shfl_xor(t2, 2);
                    t2 += __shfl_xor(t2, 4); t2 += __shfl_xor(t2, 8);
                    logit[j] = t2;
                }
                float mm = logit[0];
                #pragma unroll
                for (int j = 1; j < OUT_CAPS; ++j) mm = fmaxf(mm, logit[j]);
                float Z = 0.f, e[OUT_CAPS];
                #pragma unroll
                for (int j = 0; j < OUT_CAPS; ++j) { e[j] = expf(logit[j] - mm); Z += e[j]; }
                const float invZ = 1.0f / Z;
                #pragma unroll
                for (int j = 0; j < OUT_CAPS; ++j) s_loc[j] = fmaf(e[j] * invZ, u[j], s_loc[j]);
            }
        }
        #pragma unroll
        for (int j = 0; j < OUT_CAPS; ++j) sredf[g * JD + j * 16 + d] = s_loc[j];
        __syncthreads();
        if (tid < JD) {
            float sv = 0.f;
            #pragma unroll 8
            for (int gg = 0; gg < FB_NGROUPS; ++gg) sv += sredf[gg * JD + tid];
            float t2 = sv * sv;
            t2 += __shfl_xor(t2, 1); t2 += __shfl_xor(t2, 2);
            t2 += __shfl_xor(t2, 4); t2 += __shfl_xor(t2, 8);
            const float scale = t2 / (1.0f + t2) / sqrtf(t2 + 1e-7f);
            const float v = scale * sv;
            if (pass == 2) out[(size_t)b * JD + tid] = v;
            else vdot_lds[tid] = (pass == 0) ? v : (vdot_lds[tid] + v);
        }
        __syncthreads();
    }
}

extern "C" void kernel_launch(void* const* d_in, const int* in_sizes, int n_in,
                              void* d_out, int out_size, void* d_ws, size_t ws_size,
                              hipStream_t stream) {
    const float* x = (const float*)d_in[0];
    const float* W = (const float*)d_in[1];
    float* out = (float*)d_out;

    if (ws_size >= WS_NEED) {
        unsigned short* wht = (unsigned short*)d_ws;
        unsigned short* xht = (unsigned short*)((char*)d_ws + WHT_BYTES);
        float* spA    = (float*)((char*)d_ws + WHT_BYTES + XHT_BYTES);
        float* spB    = (float*)((char*)d_ws + WHT_BYTES + XHT_BYTES + SP_BYTES);
        float* vdot_g = (float*)((char*)d_ws + WHT_BYTES + XHT_BYTES + 2 * SP_BYTES);

        prep_all<<<PREPW_BLOCKS + PREPX_BLOCKS, 256, 0, stream>>>(
            x, W, (unsigned*)wht, (unsigned*)xht);

        const dim3 gR(NSLAB, 4);
        const int gSQ = (B_TOT * JD) / 256;   // 160

        caps_pass<0><<<gR, 256, 0, stream>>>(wht, xht, nullptr, spA);
        k_squash<0><<<gSQ, 256, 0, stream>>>(spA, vdot_g, out);
        caps_pass<1><<<gR, 256, 0, stream>>>(wht, xht, vdot_g, spB);
        k_squash<1><<<gSQ, 256, 0, stream>>>(spB, vdot_g, out);
        caps_pass<2><<<gR, 256, 0, stream>>>(wht, xht, vdot_g, spA);
        k_squash<2><<<gSQ, 256, 0, stream>>>(spA, vdot_g, out);
    } else {
        caps_routing_kernel<<<B_TOT, FB_THREADS, 0, stream>>>(x, W, out);
    }
}

// Round 11
// 73.374 us; speedup vs baseline: 7.1261x; 1.2263x over previous
//
#include <hip/hip_runtime.h>
#include <math.h>

// CapsuleLayer dynamic routing. B=256, IN=1152, K=8, J=10, D=16, 3 passes.
//
// 7 kernels:
//  prep_all : (r7/r10-verified) W -> wht bf16 [i][jd][k]*0.25 (k-replication:
//             all 4 K-quads read the same 8-k fragment -> u = 4*(x*W/4));
//             x -> xht bf16 [i][b][k]. Coalesced LDS transposes.
//  caps_pass<P>: grid (48 i-slabs x 16 b-tiles), 256 thr = 4 waves.
//             Block covers 24 i x 16 b; waves split i (6 each), W staged in
//             two 12-i LDS chunks; x staged once. Per i: 10x
//             mfma_f32_16x16x32_bf16 (C layout verified r5-r10: col=b,
//             row=d-quad, tile=j). P0: accumulator-chained MFMA, x0.1 at
//             store. P>0: logit = 4 in-lane FMA + shfl 16/32; softmax
//             in-lane, no max-sub (|L| < 6, exp safe); s += c*u.
//             4-wave LDS tree reduce (red aliases wsl) -> slab store.
//  k_squash<P>: reduce 48 slabs + squash -> vdot_g (P0: =v0, P1: +=v1) /
//             out (P2).
// Algebra: logits at pass t = (sum of previous v)·u_hat; pass 0 c = 0.1.

typedef float f32x4 __attribute__((ext_vector_type(4)));
typedef short bf16x8 __attribute__((ext_vector_type(8)));

#define B_TOT 256
#define IN_CAPS 1152
#define OUT_CAPS 10
#define JD 160

#define NSLAB 48
#define IPB 24             // i per block
#define CHI 12             // i per W chunk (2 chunks)
#define REDS 164

#define WHT_BYTES (1152ull * 160 * 8 * 2)             // 2,949,120
#define XHT_BYTES (1152ull * 256 * 8 * 2)             // 4,718,592
#define SP_BYTES  ((size_t)NSLAB * B_TOT * JD * 4)    // 7,864,320
#define VD_BYTES  ((size_t)B_TOT * JD * 4)            // 163,840
#define WS_NEED   (WHT_BYTES + XHT_BYTES + 2 * SP_BYTES + VD_BYTES)

static __device__ __forceinline__ unsigned f2bf(float f) {
    unsigned u = __float_as_uint(f);
    return (u + 0x7FFFu + ((u >> 16) & 1u)) >> 16;
}

// ---------------- coalesced preps (r7/r10-verified) ----------------
#define PREPW_BLOCKS 288   // 4 i each
#define PREPX_BLOCKS 288   // 16 i x 64 b each

__global__ __launch_bounds__(256)
void prep_all(const float* __restrict__ x, const float* __restrict__ W,
              unsigned* __restrict__ whu, unsigned* __restrict__ xhu) {
    __shared__ __align__(16) float lds[64 * 132];   // 33,792 B
    const int bid = blockIdx.x, t = threadIdx.x;

    if (bid < PREPW_BLOCKS) {
        const int i0 = bid * 4;
        const f32x4* src = (const f32x4*)(W + (size_t)i0 * 1280);
        for (int c = t; c < 1280; c += 256)
            *(f32x4*)(lds + c * 4) = src[c];          // coalesced read
        __syncthreads();
        for (int c = t; c < 2560; c += 256) {
            const int i_l = c / 640, p = c % 640;
            const int jd = p >> 2, kp = p & 3;        // k = 2*kp
            const int j = jd >> 4, d = jd & 15;
            const float* base = lds + i_l * 1280 + j * 128 + d;
            const unsigned lo = f2bf(base[(2 * kp) * 16] * 0.25f);
            const unsigned hi = f2bf(base[(2 * kp + 1) * 16] * 0.25f);
            whu[(size_t)i0 * 640 + c] = lo | (hi << 16);   // coalesced write
        }
    } else {
        const int bx = bid - PREPW_BLOCKS;
        const int it = bx >> 2;          // 72 i-tiles
        const int bt = bx & 3;           // 4 b-tiles of 64
        const int i0 = it * 16, b0 = bt * 64;
        for (int c = t; c < 2048; c += 256) {
            const int bl = c >> 5, cf = c & 31;
            f32x4 v = *(const f32x4*)(x + (size_t)(b0 + bl) * 9216 + i0 * 8 + cf * 4);
            *(f32x4*)(lds + bl * 132 + cf * 4) = v;   // coalesced read
        }
        __syncthreads();
        for (int c = t; c < 1024; c += 256) {
            const int i_l = c >> 6, b_l = c & 63;
            const float* r = lds + b_l * 132 + i_l * 8;
            uint4 o;
            o.x = f2bf(r[0]) | (f2bf(r[1]) << 16);
            o.y = f2bf(r[2]) | (f2bf(r[3]) << 16);
            o.z = f2bf(r[4]) | (f2bf(r[5]) << 16);
            o.w = f2bf(r[6]) | (f2bf(r[7]) << 16);
            ((uint4*)xhu)[(size_t)(i0 + i_l) * 256 + b0 + b_l] = o;  // 1KB runs
        }
    }
}

// ---------------- routing pass ----------------
template<int PASS>
__global__ __launch_bounds__(256, 3)
void caps_pass(const unsigned short* __restrict__ wht,
               const unsigned short* __restrict__ xht,
               const float* __restrict__ vdot_g,
               float* __restrict__ s_out) {
    __shared__ __align__(16) unsigned short wsl[CHI * 160 * 8];  // 30,720 B
    __shared__ __align__(16) unsigned short xsl[IPB * 16 * 8];   //  6,144 B
    float* red = (float*)wsl;   // aliased after compute (needs 20,992 B)

    const int t = threadIdx.x;
    const int l = t & 63;
    const int w = t >> 6;              // wave 0..3 (splits i)
    const int m = l & 15;              // b in tile / A-row / C-col
    const int q = l >> 4;              // k-quad (replicated) / d-quad (out)
    const int islab = blockIdx.x;      // 0..47
    const int btile = blockIdx.y;      // 0..15
    const int b0 = btile * 16;
    const int b = b0 + m;
    const int i0 = islab * IPB;

    // ---- stage x slab once: 24 i x 16 b ----
    {
        uint4* dX = (uint4*)xsl;
        for (int c = t; c < IPB * 16; c += 256) {
            const int il = c >> 4, bl = c & 15;
            dX[c] = ((const uint4*)xht)[(size_t)(i0 + il) * 256 + b0 + bl];
        }
    }

    // vdot fragments (i-invariant) from global (L2-hot), PASS >= 1
    f32x4 vd[10];
    if (PASS > 0) {
        #pragma unroll
        for (int jt = 0; jt < 10; ++jt)
            vd[jt] = *(const f32x4*)(vdot_g + (size_t)b * JD + jt * 16 + q * 4);
    }

    f32x4 s[10];
    #pragma unroll
    for (int jt = 0; jt < 10; ++jt) s[jt] = (f32x4){0.f, 0.f, 0.f, 0.f};

    // ---- 2 W chunks of 12 i ----
    #pragma unroll 1
    for (int ch = 0; ch < 2; ++ch) {
        __syncthreads();    // prev chunk reads done (also orders xsl writes)
        {
            const uint4* srcW = (const uint4*)wht + (size_t)(i0 + ch * CHI) * 160;
            uint4* dW = (uint4*)wsl;
            for (int c = t; c < CHI * 160; c += 256) dW[c] = srcW[c];
        }
        __syncthreads();

        #pragma unroll 1
        for (int ii = 0; ii < 3; ++ii) {
            const int il = w * 3 + ii;                 // 0..11 within chunk
            const bf16x8 xb = *(const bf16x8*)(xsl + ((ch * CHI + il) * 16 + m) * 8);

            if (PASS == 0) {
                #pragma unroll
                for (int jt = 0; jt < 10; ++jt) {
                    const bf16x8 af = *(const bf16x8*)(wsl + (il * 160 + jt * 16 + m) * 8);
                    s[jt] = __builtin_amdgcn_mfma_f32_16x16x32_bf16(af, xb, s[jt], 0, 0, 0);
                }
            } else {
                f32x4 u[10];
                #pragma unroll
                for (int jt = 0; jt < 10; ++jt) {
                    const bf16x8 af = *(const bf16x8*)(wsl + (il * 160 + jt * 16 + m) * 8);
                    u[jt] = __builtin_amdgcn_mfma_f32_16x16x32_bf16(
                                af, xb, (f32x4){0.f, 0.f, 0.f, 0.f}, 0, 0, 0);
                }
                float L[10];
                #pragma unroll
                for (int jt = 0; jt < 10; ++jt) {
                    const f32x4 p = vd[jt] * u[jt];
                    float e = (p.x + p.y) + (p.z + p.w);
                    e += __shfl_xor(e, 16);
                    e += __shfl_xor(e, 32);
                    L[jt] = e;
                }
                float Z = 0.f;
                #pragma unroll
                for (int jt = 0; jt < 10; ++jt) { L[jt] = __expf(L[jt]); Z += L[jt]; }
                const float inv = 1.0f / Z;
                #pragma unroll
                for (int jt = 0; jt < 10; ++jt) s[jt] += (L[jt] * inv) * u[jt];
            }
        }
    }

    if (PASS == 0) {
        #pragma unroll
        for (int jt = 0; jt < 10; ++jt) s[jt] *= 0.1f;
    }

    // ---- 4-wave tree reduce through LDS (red aliases wsl) ----
    __syncthreads();
    if (w >= 2) {
        float* rp = red + (w - 2) * (16 * REDS) + m * REDS + q * 4;
        #pragma unroll
        for (int jt = 0; jt < 10; ++jt) *(f32x4*)(rp + jt * 16) = s[jt];
    }
    __syncthreads();
    if (w < 2) {
        const float* rp = red + w * (16 * REDS) + m * REDS + q * 4;
        #pragma unroll
        for (int jt = 0; jt < 10; ++jt) s[jt] += *(const f32x4*)(rp + jt * 16);
    }
    __syncthreads();
    if (w == 1) {
        float* rp = red + m * REDS + q * 4;
        #pragma unroll
        for (int jt = 0; jt < 10; ++jt) *(f32x4*)(rp + jt * 16) = s[jt];
    }
    __syncthreads();
    if (w == 0) {
        const float* rp = red + m * REDS + q * 4;
        #pragma unroll
        for (int jt = 0; jt < 10; ++jt) s[jt] += *(const f32x4*)(rp + jt * 16);
        float* sp = s_out + ((size_t)islab * B_TOT + b) * JD;
        #pragma unroll
        for (int jt = 0; jt < 10; ++jt)
            *(f32x4*)(sp + jt * 16 + q * 4) = s[jt];
    }
}

// ---------------- reduce + squash ----------------
template<int PASS>
__global__ __launch_bounds__(256)
void k_squash(const float* __restrict__ s_part,
              float* __restrict__ vdot_g, float* __restrict__ out) {
    const int e = blockIdx.x * 256 + threadIdx.x;    // < 40960
    float s = 0.f;
    #pragma unroll 8
    for (int p = 0; p < NSLAB; ++p)
        s += s_part[(size_t)p * (B_TOT * JD) + e];

    float t = s * s;
    t += __shfl_xor(t, 1);
    t += __shfl_xor(t, 2);
    t += __shfl_xor(t, 4);
    t += __shfl_xor(t, 8);
    const float scale = t / (1.0f + t) / sqrtf(t + 1e-7f);
    const float v = scale * s;

    if (PASS == 0)      vdot_g[e] = v;
    else if (PASS == 1) vdot_g[e] += v;
    else                out[e] = v;
}

// ---------- fallback: round-1 fused kernel (ws too small; shouldn't happen) ----------
#define FB_NGROUPS 32
#define FB_THREADS (FB_NGROUPS * 16)
#define FB_ITERS (IN_CAPS / FB_NGROUPS)
__global__ __launch_bounds__(FB_THREADS)
void caps_routing_kernel(const float* __restrict__ x, const float* __restrict__ W,
                         float* __restrict__ out) {
    __shared__ __align__(16) float xsf[IN_CAPS * 8];
    __shared__ float sredf[FB_NGROUPS * JD];
    __shared__ float vdot_lds[JD];
    const int b = blockIdx.x, tid = threadIdx.x;
    const int g = tid >> 4, d = tid & 15;
    {
        const float4* xg = reinterpret_cast<const float4*>(x + (size_t)b * IN_CAPS * 8);
        float4* xl = reinterpret_cast<float4*>(xsf);
        for (int t = tid; t < IN_CAPS * 2; t += FB_THREADS) xl[t] = xg[t];
    }
    __syncthreads();
    for (int pass = 0; pass < 3; ++pass) {
        float vdot_reg[OUT_CAPS];
        if (pass > 0) {
            #pragma unroll
            for (int j = 0; j < OUT_CAPS; ++j) vdot_reg[j] = vdot_lds[j * 16 + d];
        }
        float s_loc[OUT_CAPS];
        #pragma unroll
        for (int j = 0; j < OUT_CAPS; ++j) s_loc[j] = 0.f;
        for (int it = 0; it < FB_ITERS; ++it) {
            const int i = it * FB_NGROUPS + g;
            float xk[8];
            {
                const float4* xr = reinterpret_cast<const float4*>(xsf + i * 8);
                float4 a0 = xr[0], a1 = xr[1];
                xk[0]=a0.x; xk[1]=a0.y; xk[2]=a0.z; xk[3]=a0.w;
                xk[4]=a1.x; xk[5]=a1.y; xk[6]=a1.z; xk[7]=a1.w;
            }
            const float* wpf = W + (size_t)i * 1280 + d;
            float u[OUT_CAPS];
            #pragma unroll
            for (int j = 0; j < OUT_CAPS; ++j) {
                float acc = 0.f;
                #pragma unroll
                for (int k = 0; k < 8; ++k) acc = fmaf(xk[k], wpf[j * 128 + k * 16], acc);
                u[j] = acc;
            }
            if (pass == 0) {
                #pragma unroll
                for (int j = 0; j < OUT_CAPS; ++j) s_loc[j] = fmaf(0.1f, u[j], s_loc[j]);
            } else {
                float logit[OUT_CAPS];
                #pragma unroll
                for (int j = 0; j < OUT_CAPS; ++j) {
                    float t2 = vdot_reg[j] * u[j];
                    t2 += __shfl_xor(t2, 1); t2 += __shfl_xor(t2, 2);
                    t2 += __shfl_xor(t2, 4); t2 += __shfl_xor(t2, 8);
                    logit[j] = t2;
                }
                float mm = logit[0];
                #pragma unroll
                for (int j = 1; j < OUT_CAPS; ++j) mm = fmaxf(mm, logit[j]);
                float Z = 0.f, e[OUT_CAPS];
                #pragma unroll
                for (int j = 0; j < OUT_CAPS; ++j) { e[j] = expf(logit[j] - mm); Z += e[j]; }
                const float invZ = 1.0f / Z;
                #pragma unroll
                for (int j = 0; j < OUT_CAPS; ++j) s_loc[j] = fmaf(e[j] * invZ, u[j], s_loc[j]);
            }
        }
        #pragma unroll
        for (int j = 0; j < OUT_CAPS; ++j) sredf[g * JD + j * 16 + d] = s_loc[j];
        __syncthreads();
        if (tid < JD) {
            float sv = 0.f;
            #pragma unroll 8
            for (int gg = 0; gg < FB_NGROUPS; ++gg) sv += sredf[gg * JD + tid];
            float t2 = sv * sv;
            t2 += __shfl_xor(t2, 1); t2 += __shfl_xor(t2, 2);
            t2 += __shfl_xor(t2, 4); t2 += __shfl_xor(t2, 8);
            const float scale = t2 / (1.0f + t2) / sqrtf(t2 + 1e-7f);
            const float v = scale * sv;
            if (pass == 2) out[(size_t)b * JD + tid] = v;
            else vdot_lds[tid] = (pass == 0) ? v : (vdot_lds[tid] + v);
        }
        __syncthreads();
    }
}

extern "C" void kernel_launch(void* const* d_in, const int* in_sizes, int n_in,
                              void* d_out, int out_size, void* d_ws, size_t ws_size,
                              hipStream_t stream) {
    const float* x = (const float*)d_in[0];
    const float* W = (const float*)d_in[1];
    float* out = (float*)d_out;

    if (ws_size >= WS_NEED) {
        unsigned short* wht = (unsigned short*)d_ws;
        unsigned short* xht = (unsigned short*)((char*)d_ws + WHT_BYTES);
        float* spA    = (float*)((char*)d_ws + WHT_BYTES + XHT_BYTES);
        float* spB    = (float*)((char*)d_ws + WHT_BYTES + XHT_BYTES + SP_BYTES);
        float* vdot_g = (float*)((char*)d_ws + WHT_BYTES + XHT_BYTES + 2 * SP_BYTES);

        prep_all<<<PREPW_BLOCKS + PREPX_BLOCKS, 256, 0, stream>>>(
            x, W, (unsigned*)wht, (unsigned*)xht);

        const dim3 gR(NSLAB, 16);
        const int gSQ = (B_TOT * JD) / 256;   // 160

        caps_pass<0><<<gR, 256, 0, stream>>>(wht, xht, nullptr, spA);
        k_squash<0><<<gSQ, 256, 0, stream>>>(spA, vdot_g, out);
        caps_pass<1><<<gR, 256, 0, stream>>>(wht, xht, vdot_g, spB);
        k_squash<1><<<gSQ, 256, 0, stream>>>(spB, vdot_g, out);
        caps_pass<2><<<gR, 256, 0, stream>>>(wht, xht, vdot_g, spA);
        k_squash<2><<<gSQ, 256, 0, stream>>>(spA, vdot_g, out);
    } else {
        caps_routing_kernel<<<B_TOT, FB_THREADS, 0, stream>>>(x, W, out);
    }
}